// Round 17
// baseline (1798.302 us; speedup 1.0000x reference)
//
#include <hip/hip_runtime.h>
#include <hip/hip_bf16.h>
#include <math.h>

#define B_   512
#define H_   512
#define FIN_ 1024
#define TS_  128

typedef __attribute__((ext_vector_type(8))) _Float16 half8;
typedef __attribute__((ext_vector_type(4))) float f32x4;
typedef __attribute__((ext_vector_type(2))) unsigned long long u64x2;

// ---------------- weight prepack (once per call), fp16 single plane ----------
// Wpkh [jt 0..31][kt 0..15][g 0..5][lane 0..63][i 0..7] fp16
// B-frag (16x16x32): lane holds B[k = kt*32 + (lane>>4)*8 + i][j = jt*16 + (lane&15)]
__global__ __launch_bounds__(384)
void pack_weights(const float* __restrict__ Wih, const float* __restrict__ Whh,
                  _Float16* __restrict__ Wpkh) {
    int jt = blockIdx.x;              // 0..31
    int kt = blockIdx.y;              // 0..15
    int g    = threadIdx.x >> 6;      // 0..5
    int lane = threadIdx.x & 63;
    int j = jt * 16 + (lane & 15);
    int k = kt * 32 + (lane >> 4) * 8;
    const float* src = (g < 3) ? &Wih[(size_t)(g * H_ + j) * H_ + k]
                               : &Whh[(size_t)((g - 3) * H_ + j) * H_ + k];
    half8 v;
#pragma unroll
    for (int i = 0; i < 8; ++i) v[i] = (_Float16)src[i];
    size_t off = ((((size_t)(jt * 16 + kt) * 6 + g)) * 64 + lane) * 8;
    *reinterpret_cast<half8*>(&Wpkh[off]) = v;
}

// WlinT[k][j] = W_lin[j][k], [1024][512]
__global__ void transpose_lin(const float* __restrict__ Wlin,
                              float* __restrict__ Wt) {
    __shared__ float t[32][33];
    int j0 = blockIdx.x * 32, k0 = blockIdx.y * 32;
    int kk = threadIdx.x, jj = threadIdx.y;
#pragma unroll
    for (int r = 0; r < 32; r += 8)
        t[jj + r][kk] = Wlin[(size_t)(j0 + jj + r) * FIN_ + k0 + kk];
    __syncthreads();
#pragma unroll
    for (int r = 0; r < 32; r += 8)
        Wt[(size_t)(k0 + jj + r) * H_ + j0 + kk] = t[kk][jj + r];
}

// ------------- h0 = x @ WlinT + b_lin (fp32; writes fp16 plane + f32 plane) --
__global__ __launch_bounds__(256)
void gemm_h0(const float* __restrict__ X, const float* __restrict__ Wt,
             const float* __restrict__ bias,
             _Float16* __restrict__ H16, float* __restrict__ H32) {
    const int BM = 32, BN = 32, BK = 32;
    __shared__ float xs[BK][BM + 2];
    __shared__ float ws[BK][BN];
    int b0 = blockIdx.y * BM, j0 = blockIdx.x * BN;
    int tid = threadIdx.x;
    int tx = tid & 15, ty = tid >> 4;
    float acc[2][2] = {};
    for (int k0 = 0; k0 < FIN_; k0 += BK) {
#pragma unroll
        for (int l = 0; l < 2; ++l) {
            int e = tid + l * 256;
            int krel = (e & 15) * 2, brel = e >> 4;
            float2 v = *(const float2*)&X[(size_t)(b0 + brel) * FIN_ + k0 + krel];
            xs[krel][brel] = v.x; xs[krel + 1][brel] = v.y;
        }
        {
            int fe = tid;
            int j4 = fe & 7, krel = fe >> 3;
            *(float4*)&ws[krel][j4 * 4] =
                *(const float4*)&Wt[(size_t)(k0 + krel) * H_ + j0 + j4 * 4];
        }
        __syncthreads();
#pragma unroll
        for (int kk = 0; kk < BK; ++kk) {
            float2 a = *(const float2*)&xs[kk][ty * 2];
            float2 w = *(const float2*)&ws[kk][tx * 2];
            acc[0][0] += a.x * w.x; acc[0][1] += a.x * w.y;
            acc[1][0] += a.y * w.x; acc[1][1] += a.y * w.y;
        }
        __syncthreads();
    }
#pragma unroll
    for (int r = 0; r < 2; ++r)
#pragma unroll
        for (int c = 0; c < 2; ++c) {
            int b = b0 + ty * 2 + r, j = j0 + tx * 2 + c;
            float v = acc[r][c] + bias[j];
            H32[(size_t)b * H_ + j] = v;
            H16[(size_t)b * H_ + j] = (_Float16)v;
        }
}

// ---------------- persistent GRU: wave-autonomous, all 128 steps -------------
// 256 blocks x 256 thr (4 waves), 1 block/CU (96KB LDS). Block = (m = bid&7
// -> 64 rows, jt = bid>>3 -> 16 cols). W for this jt lives in LDS (loaded
// once); each wave s owns rows [m*64+s*16, +16) x 16 cols x FULL K=512:
// 96 ds_read_b128 + 96 MFMA per step, C-frag holds all 6 gate values for
// each (row,col) in-lane -> epilogue fully in-register. ZERO __syncthreads
// in the loop. Flags at 16-row-slice granularity: family (m,s) = the 32
// waves (one per jt) that all read/write rows (m,s). Wave polls its 32
// family flags >= t before step t; since every reader of rows(m,s) IS a
// family member and publishes only after its loads, flag>=t also proves all
// step-(t-1) reads done -> ping-pong safe. All h/flag traffic is relaxed
// AGENT-scope at L3 (placement-independent). Waves drift independently ->
// chains overlap across the CU's 4 waves.
__global__ __launch_bounds__(256, 1)
void gru_persist(const _Float16* __restrict__ Wpkh,
                 const float* __restrict__ bp,
                 const _Float16* __restrict__ h16A, _Float16* __restrict__ h16B,
                 const float* __restrict__ h0f32,
                 float* __restrict__ out,
                 unsigned int* __restrict__ flags) {
    int bid  = blockIdx.x;
    int m    = bid & 7;            // 64-row group
    int jt   = bid >> 3;           // 0..31
    int tid  = threadIdx.x;
    int s    = tid >> 6;           // wave/slice 0..3
    int lane = tid & 63;

    __shared__ _Float16 Wlds[16 * 6 * 64 * 8];   // 98304 B

    // ---- cooperative W copy (96 KB), once; only block-wide sync ----
    {
        const float4* src = (const float4*)(Wpkh + (size_t)jt * 16 * 6 * 512);
        float4* dst = (float4*)Wlds;
#pragma unroll
        for (int i = 0; i < 24; ++i)
            dst[tid + i * 256] = src[tid + i * 256];
    }
    __syncthreads();

    unsigned int* fline = flags + (m * 4 + s) * 128;   // family (m,s): 32 flags, one line

    int r0    = m * 64 + s * 16;
    int arow  = r0 + (lane & 15);
    int akoff = (lane >> 4) * 8;
    int col   = jt * 16 + (lane & 15);
    int rb    = r0 + (lane >> 4) * 4;    // epilogue row base (rows rb..rb+3)

    float eb[6];
#pragma unroll
    for (int g = 0; g < 6; ++g) eb[g] = bp[g * H_ + col];

    float hpv[4];
#pragma unroll
    for (int v = 0; v < 4; ++v) hpv[v] = h0f32[(size_t)(rb + v) * H_ + col];

    const _Float16* cur = h16A;
    _Float16*       nxt = h16B;

    for (int t = 0; t < TS_; ++t) {
        // ---- family poll: all lanes, 32 flags (one 128B line) ----
        if (t > 0) {
            unsigned tgt = (unsigned)t;
            const unsigned int* pf = &fline[lane & 31];
            while (__hip_atomic_load(pf, __ATOMIC_RELAXED,
                                     __HIP_MEMORY_SCOPE_AGENT) < tgt)
                __builtin_amdgcn_s_sleep(1);
        }

        // ---- A-loads: 16 frags (own 16 rows x full K), agent-scope ----
        half8 a[16];
#pragma unroll
        for (int kt = 0; kt < 16; ++kt) {
            const unsigned long long* p = (const unsigned long long*)
                (cur + (size_t)arow * H_ + kt * 32 + akoff);
            u64x2 v;
            v[0] = __hip_atomic_load(p,     __ATOMIC_RELAXED, __HIP_MEMORY_SCOPE_AGENT);
            v[1] = __hip_atomic_load(p + 1, __ATOMIC_RELAXED, __HIP_MEMORY_SCOPE_AGENT);
            a[kt] = __builtin_bit_cast(half8, v);
        }

        // ---- full-K MFMA: 96 ds_read_b128 + up to 96 MFMA ----
        f32x4 acc[6] = {};
#pragma unroll 4
        for (int kt = 0; kt < 16; ++kt) {
            const half8* wl = (const half8*)&Wlds[((size_t)(kt * 6) * 64 + lane) * 8];
#pragma unroll
            for (int g = 3; g < 6; ++g) {
                half8 bf = wl[(size_t)g * 64];
                acc[g] = __builtin_amdgcn_mfma_f32_16x16x32_f16(a[kt], bf, acc[g], 0, 0, 0);
            }
            if (t > 0) {
#pragma unroll
                for (int g = 0; g < 3; ++g) {
                    half8 bf = wl[(size_t)g * 64];
                    acc[g] = __builtin_amdgcn_mfma_f32_16x16x32_f16(a[kt], bf, acc[g], 0, 0, 0);
                }
            }
        }

        // ---- in-register epilogue: 4 outputs/lane (same col, rows rb+v) ----
        float hns[4];
#pragma unroll
        for (int v = 0; v < 4; ++v) {
            float ir  = acc[0][v] + eb[0];   // t=0: acc0..2 = 0 -> gi = b_ih exactly
            float iz  = acc[1][v] + eb[1];
            float in_ = acc[2][v] + eb[2];
            float hr  = acc[3][v] + eb[3];
            float hz  = acc[4][v] + eb[4];
            float hn  = acc[5][v] + eb[5];
            float rg = 1.f / (1.f + expf(-(ir + hr)));
            float zg = 1.f / (1.f + expf(-(iz + hz)));
            float ng = tanhf(in_ + rg * hn);
            float h  = (1.f - zg) * ng + zg * hpv[v];
            hns[v] = h; hpv[v] = h;
            unsigned short hb = __builtin_bit_cast(unsigned short, (_Float16)h);
            __hip_atomic_store((unsigned short*)(nxt + (size_t)(rb + v) * H_ + col), hb,
                               __ATOMIC_RELAXED, __HIP_MEMORY_SCOPE_AGENT);
        }

        // ---- wave-local drain of own h-stores, then publish own flag ----
        if (t < TS_ - 1) {
            asm volatile("s_waitcnt vmcnt(0)" ::: "memory");
            if (lane == 0)
                __hip_atomic_store(&fline[jt], (unsigned)(t + 1),
                                   __ATOMIC_RELAXED, __HIP_MEMORY_SCOPE_AGENT);
        }

        // ---- out-stores off the critical path ----
#pragma unroll
        for (int v = 0; v < 4; ++v)
            __builtin_nontemporal_store(hns[v],
                &out[(size_t)(rb + v) * (TS_ * H_) + (size_t)t * H_ + col]);

        const _Float16* tc = cur;
        cur = nxt; nxt = (_Float16*)tc;
    }
}

extern "C" void kernel_launch(void* const* d_in, const int* in_sizes, int n_in,
                              void* d_out, int out_size, void* d_ws, size_t ws_size,
                              hipStream_t stream) {
    const float* x     = (const float*)d_in[0];
    const float* W_lin = (const float*)d_in[1];
    const float* b_lin = (const float*)d_in[2];
    const float* W_ih  = (const float*)d_in[3];
    const float* W_hh  = (const float*)d_in[4];
    const float* b_ih  = (const float*)d_in[5];
    const float* b_hh  = (const float*)d_in[6];
    float* out = (float*)d_out;

    char* wsb = (char*)d_ws;
    _Float16* Wpkh  = (_Float16*)(wsb);              // 3145728 B
    float*    WlinT = (float*)(wsb + 3145728);       // 2097152 B
    float*    bp    = (float*)(wsb + 5242880);       // 12288 B
    _Float16* h16A  = (_Float16*)(wsb + 5255168);    // 524288 B
    _Float16* h16B  = (_Float16*)(wsb + 5779456);    // 524288 B
    float*    h0f32 = (float*)(wsb + 6303744);       // 1048576 B
    unsigned int* flags = (unsigned int*)(wsb + 7352320);  // 32 lines x 512B = 16 KB

    hipMemcpyAsync(bp,        b_ih, 1536 * sizeof(float), hipMemcpyDeviceToDevice, stream);
    hipMemcpyAsync(bp + 1536, b_hh, 1536 * sizeof(float), hipMemcpyDeviceToDevice, stream);
    hipMemsetAsync(flags, 0, 32 * 128 * sizeof(unsigned int), stream);

    pack_weights <<<dim3(32, 16), 384, 0, stream>>>(W_ih, W_hh, Wpkh);
    transpose_lin<<<dim3(16, 32), dim3(32, 8), 0, stream>>>(W_lin, WlinT);

    gemm_h0<<<dim3(16, 16), 256, 0, stream>>>(x, WlinT, b_lin, h16A, h0f32);

    gru_persist<<<256, 256, 0, stream>>>(Wpkh, bp, h16A, h16B, h0f32, out, flags);
}

// Round 18
// 911.304 us; speedup vs baseline: 1.9733x; 1.9733x over previous
//
#include <hip/hip_runtime.h>
#include <hip/hip_bf16.h>
#include <math.h>

#define B_   512
#define H_   512
#define FIN_ 1024
#define TS_  128

typedef __attribute__((ext_vector_type(8))) _Float16 half8;
typedef __attribute__((ext_vector_type(4))) float f32x4;
typedef __attribute__((ext_vector_type(2))) unsigned long long u64x2;

// fast sigmoid/tanh: v_exp_f32 + v_rcp_f32 (rel err ~1e-6, far below fp16 h rounding)
static __device__ __forceinline__ float fsig(float x) {
    return __builtin_amdgcn_rcpf(1.f + __expf(-x));
}
static __device__ __forceinline__ float ftanh(float x) {
    return 1.f - 2.f * __builtin_amdgcn_rcpf(1.f + __expf(2.f * x));
}

// ---------------- weight prepack (once per call), fp16 single plane ----------
// Wpkh [jt 0..31][kt 0..15][g 0..5][lane 0..63][i 0..7] fp16
// B-frag (16x16x32): lane holds B[k = kt*32 + (lane>>4)*8 + i][j = jt*16 + (lane&15)]
__global__ __launch_bounds__(384)
void pack_weights(const float* __restrict__ Wih, const float* __restrict__ Whh,
                  _Float16* __restrict__ Wpkh) {
    int jt = blockIdx.x;              // 0..31
    int kt = blockIdx.y;              // 0..15
    int g    = threadIdx.x >> 6;      // 0..5
    int lane = threadIdx.x & 63;
    int j = jt * 16 + (lane & 15);
    int k = kt * 32 + (lane >> 4) * 8;
    const float* src = (g < 3) ? &Wih[(size_t)(g * H_ + j) * H_ + k]
                               : &Whh[(size_t)((g - 3) * H_ + j) * H_ + k];
    half8 v;
#pragma unroll
    for (int i = 0; i < 8; ++i) v[i] = (_Float16)src[i];
    size_t off = ((((size_t)(jt * 16 + kt) * 6 + g)) * 64 + lane) * 8;
    *reinterpret_cast<half8*>(&Wpkh[off]) = v;
}

// WlinT[k][j] = W_lin[j][k], [1024][512]
__global__ void transpose_lin(const float* __restrict__ Wlin,
                              float* __restrict__ Wt) {
    __shared__ float t[32][33];
    int j0 = blockIdx.x * 32, k0 = blockIdx.y * 32;
    int kk = threadIdx.x, jj = threadIdx.y;
#pragma unroll
    for (int r = 0; r < 32; r += 8)
        t[jj + r][kk] = Wlin[(size_t)(j0 + jj + r) * FIN_ + k0 + kk];
    __syncthreads();
#pragma unroll
    for (int r = 0; r < 32; r += 8)
        Wt[(size_t)(k0 + jj + r) * H_ + j0 + kk] = t[kk][jj + r];
}

// ------------- h0 = x @ WlinT + b_lin (fp32; writes fp16 plane + f32 plane) --
__global__ __launch_bounds__(256)
void gemm_h0(const float* __restrict__ X, const float* __restrict__ Wt,
             const float* __restrict__ bias,
             _Float16* __restrict__ H16, float* __restrict__ H32) {
    const int BM = 32, BN = 32, BK = 32;
    __shared__ float xs[BK][BM + 2];
    __shared__ float ws[BK][BN];
    int b0 = blockIdx.y * BM, j0 = blockIdx.x * BN;
    int tid = threadIdx.x;
    int tx = tid & 15, ty = tid >> 4;
    float acc[2][2] = {};
    for (int k0 = 0; k0 < FIN_; k0 += BK) {
#pragma unroll
        for (int l = 0; l < 2; ++l) {
            int e = tid + l * 256;
            int krel = (e & 15) * 2, brel = e >> 4;
            float2 v = *(const float2*)&X[(size_t)(b0 + brel) * FIN_ + k0 + krel];
            xs[krel][brel] = v.x; xs[krel + 1][brel] = v.y;
        }
        {
            int fe = tid;
            int j4 = fe & 7, krel = fe >> 3;
            *(float4*)&ws[krel][j4 * 4] =
                *(const float4*)&Wt[(size_t)(k0 + krel) * H_ + j0 + j4 * 4];
        }
        __syncthreads();
#pragma unroll
        for (int kk = 0; kk < BK; ++kk) {
            float2 a = *(const float2*)&xs[kk][ty * 2];
            float2 w = *(const float2*)&ws[kk][tx * 2];
            acc[0][0] += a.x * w.x; acc[0][1] += a.x * w.y;
            acc[1][0] += a.y * w.x; acc[1][1] += a.y * w.y;
        }
        __syncthreads();
    }
#pragma unroll
    for (int r = 0; r < 2; ++r)
#pragma unroll
        for (int c = 0; c < 2; ++c) {
            int b = b0 + ty * 2 + r, j = j0 + tx * 2 + c;
            float v = acc[r][c] + bias[j];
            H32[(size_t)b * H_ + j] = v;
            H16[(size_t)b * H_ + j] = (_Float16)v;
        }
}

// ---------------- persistent GRU: all 128 steps in one kernel ----------------
// R11 structure (best measured: 820us kernel), with the critical path
// shortened: (1) out-stores moved AFTER the flag publish -> they overlap the
// poll instead of sitting inside the vmcnt drain; (2) fast-math epilogue
// (__expf + v_rcp sigmoid/tanh) instead of libm expf/tanhf.
// 512 blocks x 256 thr (4 waves), 2 blocks/CU (different barrier groups ->
// one group's sync latency hides under the other's compute).
// Block = (row-group m = (bid&7)|((bid>>5)&8) -> 32 rows, jt = (bid>>3)&31).
// h exchange + flags: relaxed AGENT-scope atomics at L3 (the cross-XCD
// coherence point; placement-independent, no fences).
__global__ __launch_bounds__(256, 2)
void gru_persist(const _Float16* __restrict__ Wpkh,
                 const float* __restrict__ bp,
                 const _Float16* __restrict__ h16A, _Float16* __restrict__ h16B,
                 const float* __restrict__ h0f32,
                 float* __restrict__ out,
                 unsigned int* __restrict__ flags) {
    int bid  = blockIdx.x;
    int m    = (bid & 7) | ((bid >> 5) & 8);   // row group (16 groups x 32 rows)
    int jt   = (bid >> 3) & 31;                // 0..31
    int m0   = m * 32;
    int tid  = threadIdx.x;
    int w    = tid >> 6;           // wave 0..3
    int lane = tid & 63;

    unsigned int* gflags = flags + m * 128;   // 32 flags in one 128B line

    __shared__ float red[2][2][6][64][4];     // 24 KB

    // ---- prologue: persistent W fragments (4 kt x 6 gates, fp16) ----
    half8 Wf[4][6];
#pragma unroll
    for (int kk = 0; kk < 4; ++kk) {
        int kt = 4 * w + kk;
        const _Float16* wb = &Wpkh[((size_t)(jt * 16 + kt) * 6) * 512 + lane * 8];
#pragma unroll
        for (int g = 0; g < 6; ++g)
            Wf[kk][g] = *(const half8*)&wb[(size_t)g * 512];
    }

    // ---- epilogue mapping: thread owns 2 outputs (same row, adjacent cols) --
    int o0   = tid * 2;
    int erow = o0 >> 4;            // 0..31 block-local row
    int ecol = o0 & 15;            // even col
    int gr   = m0 + erow;          // global row
    int gc0  = jt * 16 + ecol;
    float eb0[6], eb1[6];
#pragma unroll
    for (int g = 0; g < 6; ++g) { eb0[g] = bp[g * H_ + gc0]; eb1[g] = bp[g * H_ + gc0 + 1]; }
    int emf   = erow >> 4;
    int elane = ((erow & 15) >> 2) << 4;
    int ev    = erow & 3;

    size_t i0 = (size_t)gr * H_ + gc0;     // even -> one packed u32 store
    float hp0 = h0f32[i0];
    float hp1 = h0f32[i0 + 1];

    const _Float16* cur = h16A;
    _Float16*       nxt = h16B;

    int arow  = m0 + (lane & 15);
    int akoff = (lane >> 4) * 8;

    for (int t = 0; t < TS_; ++t) {
        // ---- hoisted A-loads: agent-scope u64 pairs, L3-coherent ----
        half8 a[4][2];
#pragma unroll
        for (int kk = 0; kk < 4; ++kk) {
            int kbase = (4 * w + kk) * 32 + akoff;
#pragma unroll
            for (int mf = 0; mf < 2; ++mf) {
                const unsigned long long* p = (const unsigned long long*)
                    (cur + (size_t)(arow + 16 * mf) * H_ + kbase);
                u64x2 v;
                v[0] = __hip_atomic_load(p,     __ATOMIC_RELAXED, __HIP_MEMORY_SCOPE_AGENT);
                v[1] = __hip_atomic_load(p + 1, __ATOMIC_RELAXED, __HIP_MEMORY_SCOPE_AGENT);
                a[kk][mf] = __builtin_bit_cast(half8, v);
            }
        }

        f32x4 acc[2][6] = {};
#pragma unroll
        for (int kk = 0; kk < 4; ++kk) {
#pragma unroll
            for (int mf = 0; mf < 2; ++mf) {
                if (t > 0) {
#pragma unroll
                    for (int g = 0; g < 3; ++g)
                        acc[mf][g] = __builtin_amdgcn_mfma_f32_16x16x32_f16(a[kk][mf], Wf[kk][g], acc[mf][g], 0, 0, 0);
                }
#pragma unroll
                for (int g = 3; g < 6; ++g)
                    acc[mf][g] = __builtin_amdgcn_mfma_f32_16x16x32_f16(a[kk][mf], Wf[kk][g], acc[mf][g], 0, 0, 0);
            }
        }

        // ---- split-K reduction: 4 waves -> 2 rounds (R11 layout) ----
        if (w >= 2) {
#pragma unroll
            for (int mf = 0; mf < 2; ++mf)
#pragma unroll
                for (int g = 0; g < 6; ++g)
                    *(f32x4*)&red[w - 2][mf][g][lane][0] = acc[mf][g];
        }
        __syncthreads();
        if (w < 2) {
#pragma unroll
            for (int mf = 0; mf < 2; ++mf)
#pragma unroll
                for (int g = 0; g < 6; ++g)
                    acc[mf][g] += *(const f32x4*)&red[w][mf][g][lane][0];
        }
        __syncthreads();
        if (w == 1) {
#pragma unroll
            for (int mf = 0; mf < 2; ++mf)
#pragma unroll
                for (int g = 0; g < 6; ++g)
                    *(f32x4*)&red[0][mf][g][lane][0] = acc[mf][g];
        }
        __syncthreads();
        if (w == 0) {
#pragma unroll
            for (int mf = 0; mf < 2; ++mf)
#pragma unroll
                for (int g = 0; g < 6; ++g) {
                    acc[mf][g] += *(const f32x4*)&red[0][mf][g][lane][0];
                    *(f32x4*)&red[1][mf][g][lane][0] = acc[mf][g];
                }
        }
        __syncthreads();

        // ---- epilogue: fast-math gate computation; ONLY the h-store issued --
        float hn0, hn1;
        {
            float v0[6], v1[6];
#pragma unroll
            for (int g = 0; g < 6; ++g) {
                v0[g] = red[1][emf][g][elane + ecol][ev];
                v1[g] = red[1][emf][g][elane + ecol + 1][ev];
            }
            float rg0 = fsig((v0[0] + eb0[0]) + (v0[3] + eb0[3]));
            float zg0 = fsig((v0[1] + eb0[1]) + (v0[4] + eb0[4]));
            float ng0 = ftanh((v0[2] + eb0[2]) + rg0 * (v0[5] + eb0[5]));
            hn0 = (1.f - zg0) * ng0 + zg0 * hp0;

            float rg1 = fsig((v1[0] + eb1[0]) + (v1[3] + eb1[3]));
            float zg1 = fsig((v1[1] + eb1[1]) + (v1[4] + eb1[4]));
            float ng1 = ftanh((v1[2] + eb1[2]) + rg1 * (v1[5] + eb1[5]));
            hn1 = (1.f - zg1) * ng1 + zg1 * hp1;

            unsigned short s0 = __builtin_bit_cast(unsigned short, (_Float16)hn0);
            unsigned short s1 = __builtin_bit_cast(unsigned short, (_Float16)hn1);
            unsigned pk = (unsigned)s0 | ((unsigned)s1 << 16);
            __hip_atomic_store((unsigned*)(nxt + i0), pk,
                               __ATOMIC_RELAXED, __HIP_MEMORY_SCOPE_AGENT);
            hp0 = hn0; hp1 = hn1;
        }

        if (t < TS_ - 1) {
            // drain h-stores only (out-stores not yet issued), join, publish
            asm volatile("s_waitcnt vmcnt(0)" ::: "memory");
            __syncthreads();
            if (tid == 0)
                __hip_atomic_store(&gflags[jt], (unsigned)(t + 1),
                                   __ATOMIC_RELAXED, __HIP_MEMORY_SCOPE_AGENT);
            // out-stores AFTER publish: they fly during the poll (off the chain)
            {
                size_t oo = (size_t)gr * (TS_ * H_) + (size_t)t * H_;
                __builtin_nontemporal_store(hn0, &out[oo + gc0]);
                __builtin_nontemporal_store(hn1, &out[oo + gc0 + 1]);
            }
            if (w == 0 && lane < 32) {
                unsigned target = (unsigned)(t + 1);
                while (__hip_atomic_load(&gflags[lane], __ATOMIC_RELAXED,
                                         __HIP_MEMORY_SCOPE_AGENT) < target)
                    __builtin_amdgcn_s_sleep(1);
            }
            __syncthreads();
            const _Float16* tc = cur;
            cur = nxt; nxt = (_Float16*)tc;
        } else {
            size_t oo = (size_t)gr * (TS_ * H_) + (size_t)t * H_;
            __builtin_nontemporal_store(hn0, &out[oo + gc0]);
            __builtin_nontemporal_store(hn1, &out[oo + gc0 + 1]);
        }
    }
}

extern "C" void kernel_launch(void* const* d_in, const int* in_sizes, int n_in,
                              void* d_out, int out_size, void* d_ws, size_t ws_size,
                              hipStream_t stream) {
    const float* x     = (const float*)d_in[0];
    const float* W_lin = (const float*)d_in[1];
    const float* b_lin = (const float*)d_in[2];
    const float* W_ih  = (const float*)d_in[3];
    const float* W_hh  = (const float*)d_in[4];
    const float* b_ih  = (const float*)d_in[5];
    const float* b_hh  = (const float*)d_in[6];
    float* out = (float*)d_out;

    char* wsb = (char*)d_ws;
    _Float16* Wpkh  = (_Float16*)(wsb);              // 3145728 B
    float*    WlinT = (float*)(wsb + 3145728);       // 2097152 B
    float*    bp    = (float*)(wsb + 5242880);       // 12288 B
    _Float16* h16A  = (_Float16*)(wsb + 5255168);    // 524288 B
    _Float16* h16B  = (_Float16*)(wsb + 5779456);    // 524288 B
    float*    h0f32 = (float*)(wsb + 6303744);       // 1048576 B
    unsigned int* flags = (unsigned int*)(wsb + 7352320);  // 16 x 128 uints

    hipMemcpyAsync(bp,        b_ih, 1536 * sizeof(float), hipMemcpyDeviceToDevice, stream);
    hipMemcpyAsync(bp + 1536, b_hh, 1536 * sizeof(float), hipMemcpyDeviceToDevice, stream);
    hipMemsetAsync(flags, 0, 16 * 128 * sizeof(unsigned int), stream);

    pack_weights <<<dim3(32, 16), 384, 0, stream>>>(W_ih, W_hh, Wpkh);
    transpose_lin<<<dim3(16, 32), dim3(32, 8), 0, stream>>>(W_lin, WlinT);

    gemm_h0<<<dim3(16, 16), 256, 0, stream>>>(x, WlinT, b_lin, h16A, h0f32);

    gru_persist<<<512, 256, 0, stream>>>(Wpkh, bp, h16A, h16B, h0f32, out, flags);
}